// Round 5
// baseline (883.974 us; speedup 1.0000x reference)
//
#include <hip/hip_runtime.h>
#include <cstdint>

#define P2 2654435761u
#define P3 805459861u
#define HMASK 524287u

// Native clang vector types -- __builtin_nontemporal_* requires these.
typedef float nfloat4 __attribute__((ext_vector_type(4)));
typedef float nfloat2 __attribute__((ext_vector_type(2)));
// 8B-aligned float4 view for the dense-grid z-pair load (address is
// 8B-aligned; gfx950 global_load_dwordx4 only needs dword alignment).
typedef nfloat4 uf4 __attribute__((aligned(8)));

// int(16 * exp((ln2048-ln16)/15)**l), hand-verified against IEEE-double
// semantics of the numpy reference. All values EVEN => rm1 odd.
__constant__ int RES[16] = {16, 22, 30, 42, 58, 80, 111, 153,
                            212, 294, 406, 561, 776, 1072, 1482, 2048};

// Dense un-hashed grids for levels 0..3 (z fastest). Total footprint
// 115832 float2 = 926 KB -- deliberately small so the combined gather
// working set (4 MB hashed table + 0.93 MB dense) stays ~L2-sized.
// (Round-3 lesson: a 20 MB working set pushed every gather to HBM.)
#define D_N0 4096      // 16^3
#define D_N1 10648     // 22^3
#define D_N2 27000     // 30^3
#define D_N3 74088     // 42^3
#define D_O0 0
#define D_O1 4096
#define D_O2 14744
#define D_O3 41744
#define D_TOTAL 115832

__global__ __launch_bounds__(256) void build_dense(
    const float2* __restrict__ tbl, float2* __restrict__ D)
{
    int idx = blockIdx.x * 256 + threadIdx.x;
    if (idx >= D_TOTAL) return;
    int r, base;
    if (idx < D_O1)      { r = 16; base = D_O0; }
    else if (idx < D_O2) { r = 22; base = D_O1; }
    else if (idx < D_O3) { r = 30; base = D_O2; }
    else                 { r = 42; base = D_O3; }
    int k = idx - base;
    int z = k % r; int xy = k / r;
    int y = xy % r; int x = xy / r;
    uint32_t h = ((uint32_t)x ^ (uint32_t)y * P2 ^ (uint32_t)z * P3) & HMASK;
    D[idx] = tbl[h];
}

// One thread per (point, level), t = i*16 + l (point-major: coalesced
// output stores). Levels 0..3 read the dense grids (4 z-pair loads,
// L1-friendly 926 KB footprint); levels 4..15 use the hashed table with
// the even-x0 float4 pair merge (hash delta x0^(x0+1)==1 -> same aligned
// float4). Hashed gathers are nontemporal: L1 hit rate on a random 4 MB
// table is ~1%, so L1 fills are pure L2-bandwidth waste.
__global__ __launch_bounds__(256) void hash_enc_kernel(
    const float* __restrict__ pos, const float2* __restrict__ tbl,
    const float2* __restrict__ D, float2* __restrict__ out, int n, int useD)
{
    const nfloat4* __restrict__ tbl4 = (const nfloat4*)tbl;

    __shared__ int sres[16];
    __shared__ float spos[48];   // 16 points * 3 coords for this block

    const int tid = threadIdx.x;
    if (tid < 16) sres[tid] = RES[tid];

    // Stage the block's 16 positions: 12 float4 nt loads instead of
    // 768 broadcast lane-requests.
    const int p0 = blockIdx.x * 16;
    if (p0 + 16 <= n) {
        if (tid < 12) {
            nfloat4 v = __builtin_nontemporal_load(
                (const nfloat4*)(pos + (size_t)p0 * 3) + tid);
            ((nfloat4*)spos)[tid] = v;
        }
    } else {
        if (tid < 48) {
            int gi = p0 * 3 + tid;
            spos[tid] = (gi < 3 * n) ? pos[gi] : 0.0f;
        }
    }
    __syncthreads();

    const int t = blockIdx.x * 256 + tid;
    const int i = t >> 4;        // point index
    const int l = t & 15;        // level index
    if (i >= n) return;
    const int li = tid >> 4;     // local point 0..15

    float x = (spos[3 * li + 0] + 1.0f) * 0.5f;
    float y = (spos[3 * li + 1] + 1.0f) * 0.5f;
    float z = (spos[3 * li + 2] + 1.0f) * 0.5f;

    const int r = sres[l];
    const int rm1 = r - 1;
    const float rf = (float)rm1;

    float sx = x * rf, sy = y * rf, sz = z * rf;
    float fx = floorf(sx), fy = floorf(sy), fz = floorf(sz);
    float wx = sx - fx, wy = sy - fy, wz = sz - fz;
    int x0 = (int)fx, y0 = (int)fy, z0 = (int)fz;
    // p in [0,1) strictly (positions uniform in [-1,1)) => x0 <= r-2 and
    // the clamps below never bind; kept for safety.
    int x0c = min(max(x0, 0), rm1), x1c = min(max(x0 + 1, 0), rm1);
    int y0c = min(max(y0, 0), rm1), y1c = min(max(y0 + 1, 0), rm1);
    int z0c = min(max(z0, 0), rm1), z1c = min(max(z0 + 1, 0), rm1);

    float2 c000, c001, c010, c011, c100, c101, c110, c111;

    if (useD && l < 4) {
        // ---- dense path: 4 loads fetch all 8 corners (z-pairs) ----
        const int dbase = (l == 0) ? D_O0 : (l == 1) ? D_O1
                        : (l == 2) ? D_O2 : D_O3;
        const float2* __restrict__ Dl = D + dbase;
        int i00 = (x0c * r + y0c) * r + z0c;   // (x0,y0,z0)
        int i01 = (x0c * r + y1c) * r + z0c;   // (x0,y1,z0)
        int i10 = (x1c * r + y0c) * r + z0c;   // (x1,y0,z0)
        int i11 = (x1c * r + y1c) * r + z0c;   // (x1,y1,z0)
        nfloat4 q00 = *(const uf4*)(Dl + i00);
        nfloat4 q01 = *(const uf4*)(Dl + i01);
        nfloat4 q10 = *(const uf4*)(Dl + i10);
        nfloat4 q11 = *(const uf4*)(Dl + i11);
        c000 = make_float2(q00.x, q00.y); c001 = make_float2(q00.z, q00.w);
        c010 = make_float2(q01.x, q01.y); c011 = make_float2(q01.z, q01.w);
        c100 = make_float2(q10.x, q10.y); c101 = make_float2(q10.z, q10.w);
        c110 = make_float2(q11.x, q11.y); c111 = make_float2(q11.z, q11.w);
    } else {
        // ---- hashed path (levels 4..15) ----
        // low 19 bits of the int64 hash == low 19 bits of the uint32 hash
        uint32_t hy0 = (uint32_t)y0c * P2, hy1 = (uint32_t)y1c * P2;
        uint32_t hz0 = (uint32_t)z0c * P3, hz1 = (uint32_t)z1c * P3;
        uint32_t m00 = hy0 ^ hz0;   // (y0,z0)
        uint32_t m01 = hy0 ^ hz1;   // (y0,z1)
        uint32_t m10 = hy1 ^ hz0;   // (y1,z0)
        uint32_t m11 = hy1 ^ hz1;   // (y1,z1)

        uint32_t hx0 = (uint32_t)x0c;
        uint32_t j000 = (hx0 ^ m00) & HMASK;
        uint32_t j001 = (hx0 ^ m01) & HMASK;
        uint32_t j010 = (hx0 ^ m10) & HMASK;
        uint32_t j011 = (hx0 ^ m11) & HMASK;

        // 4 pair loads (nt: don't allocate L1): x0 corner in one half;
        // for even x0 the other half IS the x1 corner (h^1).
        nfloat4 q00 = __builtin_nontemporal_load(tbl4 + (j000 >> 1));
        nfloat4 q01 = __builtin_nontemporal_load(tbl4 + (j001 >> 1));
        nfloat4 q10 = __builtin_nontemporal_load(tbl4 + (j010 >> 1));
        nfloat4 q11 = __builtin_nontemporal_load(tbl4 + (j011 >> 1));

        bool b00 = (j000 & 1), b01 = (j001 & 1);
        bool b10 = (j010 & 1), b11 = (j011 & 1);
        c000 = b00 ? make_float2(q00.z, q00.w) : make_float2(q00.x, q00.y);
        c100 = b00 ? make_float2(q00.x, q00.y) : make_float2(q00.z, q00.w);
        c001 = b01 ? make_float2(q01.z, q01.w) : make_float2(q01.x, q01.y);
        c101 = b01 ? make_float2(q01.x, q01.y) : make_float2(q01.z, q01.w);
        c010 = b10 ? make_float2(q10.z, q10.w) : make_float2(q10.x, q10.y);
        c110 = b10 ? make_float2(q10.x, q10.y) : make_float2(q10.z, q10.w);
        c011 = b11 ? make_float2(q11.z, q11.w) : make_float2(q11.x, q11.y);
        c111 = b11 ? make_float2(q11.x, q11.y) : make_float2(q11.z, q11.w);

        // Odd x0: fetch the true x1 corners under exec mask.
        if (x0c & 1) {
            uint32_t hx1 = (uint32_t)x1c;
            const nfloat2* t2 = (const nfloat2*)tbl;
            nfloat2 a = __builtin_nontemporal_load(t2 + ((hx1 ^ m00) & HMASK));
            nfloat2 b = __builtin_nontemporal_load(t2 + ((hx1 ^ m01) & HMASK));
            nfloat2 c = __builtin_nontemporal_load(t2 + ((hx1 ^ m10) & HMASK));
            nfloat2 d = __builtin_nontemporal_load(t2 + ((hx1 ^ m11) & HMASK));
            c100 = make_float2(a.x, a.y);
            c101 = make_float2(b.x, b.y);
            c110 = make_float2(c.x, c.y);
            c111 = make_float2(d.x, d.y);
        }
    }

    float ux = 1.0f - wx, uy = 1.0f - wy, uz = 1.0f - wz;
    float w00 = ux * uy, w01 = ux * wy, w10 = wx * uy, w11 = wx * wy;
    float f0, f1;
    f0  = (w00 * uz) * c000.x; f1  = (w00 * uz) * c000.y;
    f0 += (w00 * wz) * c001.x; f1 += (w00 * wz) * c001.y;
    f0 += (w01 * uz) * c010.x; f1 += (w01 * uz) * c010.y;
    f0 += (w01 * wz) * c011.x; f1 += (w01 * wz) * c011.y;
    f0 += (w10 * uz) * c100.x; f1 += (w10 * uz) * c100.y;
    f0 += (w10 * wz) * c101.x; f1 += (w10 * wz) * c101.y;
    f0 += (w11 * uz) * c110.x; f1 += (w11 * uz) * c110.y;
    f0 += (w11 * wz) * c111.x; f1 += (w11 * wz) * c111.y;

    // 134 MB write-once output: nontemporal, keep the table L2-resident.
    nfloat2 rr; rr.x = f0; rr.y = f1;
    __builtin_nontemporal_store(rr, (nfloat2*)&out[t]);
}

extern "C" void kernel_launch(void* const* d_in, const int* in_sizes, int n_in,
                              void* d_out, int out_size, void* d_ws, size_t ws_size,
                              hipStream_t stream) {
    const float* pos = (const float*)d_in[0];
    const float2* tbl = (const float2*)d_in[1];
    float2* out = (float2*)d_out;
    int n = in_sizes[0] / 3;

    // Dense low-level grids live in the workspace (926 KB).
    int useD = (ws_size >= (size_t)(D_TOTAL * sizeof(float2))) ? 1 : 0;
    float2* D = (float2*)d_ws;
    if (useD) {
        build_dense<<<dim3((D_TOTAL + 255) / 256), dim3(256), 0, stream>>>(tbl, D);
    }

    long long total = (long long)n * 16;
    dim3 grid((unsigned)((total + 255) / 256)), block(256);
    hash_enc_kernel<<<grid, block, 0, stream>>>(pos, tbl, D, out, n, useD);
}

// Round 6
// 572.934 us; speedup vs baseline: 1.5429x; 1.5429x over previous
//
#include <hip/hip_runtime.h>
#include <cstdint>

#define P2 2654435761u
#define P3 805459861u
#define HMASK 524287u

// Native clang vector types -- __builtin_nontemporal_* requires these.
// NB round-5 lesson: nt LOADS bypass L2 on gfx950 (FETCH 82MB -> 1.1GB,
// dur 424 -> 775 us). nt is only safe for write-once stores / read-once
// streams. Table gathers must be plain loads so the table stays L2-resident.
typedef float nfloat4 __attribute__((ext_vector_type(4)));
typedef float nfloat2 __attribute__((ext_vector_type(2)));
// 8B-aligned float4 view for the dense-grid z-pair load (gfx950
// global_load_dwordx4 only needs dword alignment).
typedef nfloat4 uf4 __attribute__((aligned(8)));

// int(16 * exp((ln2048-ln16)/15)**l), hand-verified against IEEE-double
// semantics of the numpy reference. All values EVEN => rm1 odd.
__constant__ int RES[16] = {16, 22, 30, 42, 58, 80, 111, 153,
                            212, 294, 406, 561, 776, 1072, 1482, 2048};

// Dense un-hashed grids for levels 0..3 (z fastest). Total footprint
// 115832 float2 = 926 KB; l=0 (32 KB) fits L1, l<=3 stays L2-resident
// alongside the 4 MB hashed table.
#define D_O0 0
#define D_O1 4096      // + 16^3
#define D_O2 14744     // + 22^3
#define D_O3 41744     // + 30^3
#define D_TOTAL 115832 // + 42^3

__global__ __launch_bounds__(256) void build_dense(
    const float2* __restrict__ tbl, float2* __restrict__ D)
{
    int idx = blockIdx.x * 256 + threadIdx.x;
    if (idx >= D_TOTAL) return;
    int r, base;
    if (idx < D_O1)      { r = 16; base = D_O0; }
    else if (idx < D_O2) { r = 22; base = D_O1; }
    else if (idx < D_O3) { r = 30; base = D_O2; }
    else                 { r = 42; base = D_O3; }
    int k = idx - base;
    int z = k % r; int xy = k / r;
    int y = xy % r; int x = xy / r;
    uint32_t h = ((uint32_t)x ^ (uint32_t)y * P2 ^ (uint32_t)z * P3) & HMASK;
    D[idx] = tbl[h];
}

// One thread per (point, level), t = i*16 + l (point-major: coalesced
// output stores). Levels 0..3 read the dense grids (4 z-pair loads);
// levels 4..15 use the hashed table with the even-x0 float4 pair merge
// (hash delta x0^(x0+1)==1 -> same aligned float4 pair).
__global__ __launch_bounds__(256) void hash_enc_kernel(
    const float* __restrict__ pos, const float2* __restrict__ tbl,
    const float2* __restrict__ D, float2* __restrict__ out, int n, int useD)
{
    const float4* __restrict__ tbl4 = (const float4*)tbl;

    __shared__ int sres[16];
    __shared__ float spos[48];   // 16 points * 3 coords for this block

    const int tid = threadIdx.x;
    if (tid < 16) sres[tid] = RES[tid];

    // Stage the block's 16 positions: 12 float4 nt loads (read-once
    // stream) instead of 768 broadcast lane-requests.
    const int p0 = blockIdx.x * 16;
    if (p0 + 16 <= n) {
        if (tid < 12) {
            nfloat4 v = __builtin_nontemporal_load(
                (const nfloat4*)(pos + (size_t)p0 * 3) + tid);
            ((nfloat4*)spos)[tid] = v;
        }
    } else {
        if (tid < 48) {
            int gi = p0 * 3 + tid;
            spos[tid] = (gi < 3 * n) ? pos[gi] : 0.0f;
        }
    }
    __syncthreads();

    const int t = blockIdx.x * 256 + tid;
    const int i = t >> 4;        // point index
    const int l = t & 15;        // level index
    if (i >= n) return;
    const int li = tid >> 4;     // local point 0..15

    float x = (spos[3 * li + 0] + 1.0f) * 0.5f;
    float y = (spos[3 * li + 1] + 1.0f) * 0.5f;
    float z = (spos[3 * li + 2] + 1.0f) * 0.5f;

    const int r = sres[l];
    const int rm1 = r - 1;
    const float rf = (float)rm1;

    float sx = x * rf, sy = y * rf, sz = z * rf;
    float fx = floorf(sx), fy = floorf(sy), fz = floorf(sz);
    float wx = sx - fx, wy = sy - fy, wz = sz - fz;
    int x0 = (int)fx, y0 = (int)fy, z0 = (int)fz;
    // p in [0,1) strictly => clamps never bind; kept for safety.
    int x0c = min(max(x0, 0), rm1), x1c = min(max(x0 + 1, 0), rm1);
    int y0c = min(max(y0, 0), rm1), y1c = min(max(y0 + 1, 0), rm1);
    int z0c = min(max(z0, 0), rm1), z1c = min(max(z0 + 1, 0), rm1);

    float2 c000, c001, c010, c011, c100, c101, c110, c111;

    if (useD && l < 4) {
        // ---- dense path: 4 z-pair loads fetch all 8 corners ----
        const int dbase = (l == 0) ? D_O0 : (l == 1) ? D_O1
                        : (l == 2) ? D_O2 : D_O3;
        const float2* __restrict__ Dl = D + dbase;
        int i00 = (x0c * r + y0c) * r + z0c;   // (x0,y0,z0)
        int i01 = (x0c * r + y1c) * r + z0c;   // (x0,y1,z0)
        int i10 = (x1c * r + y0c) * r + z0c;   // (x1,y0,z0)
        int i11 = (x1c * r + y1c) * r + z0c;   // (x1,y1,z0)
        nfloat4 q00 = *(const uf4*)(Dl + i00);
        nfloat4 q01 = *(const uf4*)(Dl + i01);
        nfloat4 q10 = *(const uf4*)(Dl + i10);
        nfloat4 q11 = *(const uf4*)(Dl + i11);
        c000 = make_float2(q00.x, q00.y); c001 = make_float2(q00.z, q00.w);
        c010 = make_float2(q01.x, q01.y); c011 = make_float2(q01.z, q01.w);
        c100 = make_float2(q10.x, q10.y); c101 = make_float2(q10.z, q10.w);
        c110 = make_float2(q11.x, q11.y); c111 = make_float2(q11.z, q11.w);
    } else {
        // ---- hashed path (levels 4..15), plain loads: L2-resident ----
        // low 19 bits of the int64 hash == low 19 bits of the uint32 hash
        uint32_t hy0 = (uint32_t)y0c * P2, hy1 = (uint32_t)y1c * P2;
        uint32_t hz0 = (uint32_t)z0c * P3, hz1 = (uint32_t)z1c * P3;
        uint32_t m00 = hy0 ^ hz0;   // (y0,z0)
        uint32_t m01 = hy0 ^ hz1;   // (y0,z1)
        uint32_t m10 = hy1 ^ hz0;   // (y1,z0)
        uint32_t m11 = hy1 ^ hz1;   // (y1,z1)

        uint32_t hx0 = (uint32_t)x0c;
        uint32_t j000 = (hx0 ^ m00) & HMASK;
        uint32_t j001 = (hx0 ^ m01) & HMASK;
        uint32_t j010 = (hx0 ^ m10) & HMASK;
        uint32_t j011 = (hx0 ^ m11) & HMASK;

        // 4 pair loads: x0 corner in one half; for even x0 the other
        // half IS the x1 corner (h^1). All independent.
        float4 q00 = tbl4[j000 >> 1];
        float4 q01 = tbl4[j001 >> 1];
        float4 q10 = tbl4[j010 >> 1];
        float4 q11 = tbl4[j011 >> 1];

        bool b00 = (j000 & 1), b01 = (j001 & 1);
        bool b10 = (j010 & 1), b11 = (j011 & 1);
        c000 = b00 ? make_float2(q00.z, q00.w) : make_float2(q00.x, q00.y);
        c100 = b00 ? make_float2(q00.x, q00.y) : make_float2(q00.z, q00.w);
        c001 = b01 ? make_float2(q01.z, q01.w) : make_float2(q01.x, q01.y);
        c101 = b01 ? make_float2(q01.x, q01.y) : make_float2(q01.z, q01.w);
        c010 = b10 ? make_float2(q10.z, q10.w) : make_float2(q10.x, q10.y);
        c110 = b10 ? make_float2(q10.x, q10.y) : make_float2(q10.z, q10.w);
        c011 = b11 ? make_float2(q11.z, q11.w) : make_float2(q11.x, q11.y);
        c111 = b11 ? make_float2(q11.x, q11.y) : make_float2(q11.z, q11.w);

        // Odd x0: fetch the true x1 corners under exec mask.
        if (x0c & 1) {
            uint32_t hx1 = (uint32_t)x1c;
            c100 = tbl[(hx1 ^ m00) & HMASK];
            c101 = tbl[(hx1 ^ m01) & HMASK];
            c110 = tbl[(hx1 ^ m10) & HMASK];
            c111 = tbl[(hx1 ^ m11) & HMASK];
        }
    }

    float ux = 1.0f - wx, uy = 1.0f - wy, uz = 1.0f - wz;
    float w00 = ux * uy, w01 = ux * wy, w10 = wx * uy, w11 = wx * wy;
    float f0, f1;
    f0  = (w00 * uz) * c000.x; f1  = (w00 * uz) * c000.y;
    f0 += (w00 * wz) * c001.x; f1 += (w00 * wz) * c001.y;
    f0 += (w01 * uz) * c010.x; f1 += (w01 * uz) * c010.y;
    f0 += (w01 * wz) * c011.x; f1 += (w01 * wz) * c011.y;
    f0 += (w10 * uz) * c100.x; f1 += (w10 * uz) * c100.y;
    f0 += (w10 * wz) * c101.x; f1 += (w10 * wz) * c101.y;
    f0 += (w11 * uz) * c110.x; f1 += (w11 * uz) * c110.y;
    f0 += (w11 * wz) * c111.x; f1 += (w11 * wz) * c111.y;

    // 134 MB write-once output: nt store (safe -- round 2 verified the
    // table stays L2-resident with this), keeps L2 free for gathers.
    nfloat2 rr; rr.x = f0; rr.y = f1;
    __builtin_nontemporal_store(rr, (nfloat2*)&out[t]);
}

extern "C" void kernel_launch(void* const* d_in, const int* in_sizes, int n_in,
                              void* d_out, int out_size, void* d_ws, size_t ws_size,
                              hipStream_t stream) {
    const float* pos = (const float*)d_in[0];
    const float2* tbl = (const float2*)d_in[1];
    float2* out = (float2*)d_out;
    int n = in_sizes[0] / 3;

    // Dense low-level grids live in the workspace (926 KB).
    int useD = (ws_size >= (size_t)(D_TOTAL * sizeof(float2))) ? 1 : 0;
    float2* D = (float2*)d_ws;
    if (useD) {
        build_dense<<<dim3((D_TOTAL + 255) / 256), dim3(256), 0, stream>>>(tbl, D);
    }

    long long total = (long long)n * 16;
    dim3 grid((unsigned)((total + 255) / 256)), block(256);
    hash_enc_kernel<<<grid, block, 0, stream>>>(pos, tbl, D, out, n, useD);
}

// Round 7
// 525.637 us; speedup vs baseline: 1.6817x; 1.0900x over previous
//
#include <hip/hip_runtime.h>
#include <cstdint>

#define P2 2654435761u
#define P3 805459861u
#define HMASK 524287u

// nt builtins require native clang vector types.
// Round-5 lesson: nt LOADS bypass L2 on gfx950 (FETCH 82MB -> 1.1GB).
// nt only on write-once output stores + read-once position stream.
// Round-6 lesson: gather working set must stay EXACTLY the 4MB table --
// per-XCD L2 is 4MB; adding even 926KB of side tables thrashes
// (FETCH 82MB -> 686MB). No auxiliary tables.
typedef float nfloat4 __attribute__((ext_vector_type(4)));
typedef float nfloat2 __attribute__((ext_vector_type(2)));

// int(16 * exp((ln2048-ln16)/15)**l), hand-verified against IEEE-double
// semantics of the numpy reference. All values EVEN => rm1 odd => even x0
// never clamp-limited, which the x-pair merge relies on.
__constant__ int RES[16] = {16, 22, 30, 42, 58, 80, 111, 153,
                            212, 294, 406, 561, 776, 1072, 1482, 2048};

// Two (point,level) items per thread: same point i, levels l and l+8.
// Rationale: at VGPR=20 the single-item kernel is latency*concurrency
// bound (0.37 req/cyc/CU with ~28 waves x ~4.5 loads in flight / ~300cy
// L2 round trip). Doubling per-thread load MLP doubles in-flight
// requests; VGPR budget for 8 waves/SIMD is 64, so headroom is free.
//
// Block = 256 threads = 32 points x 8 level-pairs.
// Per item: hash = x ^ y*P2 ^ z*P3 (prime 1 on x) => for even x0 the two
// x-corners are the SAME aligned float4 pair (h, h^1): 4 pair loads fetch
// all 8 corners. Odd x0 (50%): 4 extra float2 fallback loads, exec-masked.
// All 16(+8) loads of both items issue before any consumption.
#define ADDR(S, LVL)                                                         \
    const int rm1##S = sres[LVL] - 1;                                        \
    const float rf##S = (float)rm1##S;                                       \
    float sx##S = x * rf##S, sy##S = y * rf##S, sz##S = z * rf##S;           \
    float fx##S = floorf(sx##S), fy##S = floorf(sy##S), fz##S = floorf(sz##S);\
    float wx##S = sx##S - fx##S, wy##S = sy##S - fy##S, wz##S = sz##S - fz##S;\
    int x0##S = (int)fx##S, y0##S = (int)fy##S, z0##S = (int)fz##S;          \
    int x0c##S = min(max(x0##S, 0), rm1##S);                                 \
    int x1c##S = min(max(x0##S + 1, 0), rm1##S);                             \
    int y0c##S = min(max(y0##S, 0), rm1##S);                                 \
    int y1c##S = min(max(y0##S + 1, 0), rm1##S);                             \
    int z0c##S = min(max(z0##S, 0), rm1##S);                                 \
    int z1c##S = min(max(z0##S + 1, 0), rm1##S);                             \
    uint32_t hy0##S = (uint32_t)y0c##S * P2, hy1##S = (uint32_t)y1c##S * P2; \
    uint32_t hz0##S = (uint32_t)z0c##S * P3, hz1##S = (uint32_t)z1c##S * P3; \
    uint32_t m00##S = hy0##S ^ hz0##S, m01##S = hy0##S ^ hz1##S;             \
    uint32_t m10##S = hy1##S ^ hz0##S, m11##S = hy1##S ^ hz1##S;             \
    uint32_t j000##S = ((uint32_t)x0c##S ^ m00##S) & HMASK;                  \
    uint32_t j001##S = ((uint32_t)x0c##S ^ m01##S) & HMASK;                  \
    uint32_t j010##S = ((uint32_t)x0c##S ^ m10##S) & HMASK;                  \
    uint32_t j011##S = ((uint32_t)x0c##S ^ m11##S) & HMASK;                  \
    bool odd##S = (x0c##S & 1);

#define PAIRLOAD(S)                                                          \
    float4 q00##S = tbl4[j000##S >> 1];                                      \
    float4 q01##S = tbl4[j001##S >> 1];                                      \
    float4 q10##S = tbl4[j010##S >> 1];                                      \
    float4 q11##S = tbl4[j011##S >> 1];

// Fallback loads into zero-inited temps (unselected when !odd).
#define FALLBACK(S)                                                          \
    float2 e0##S = make_float2(0.f, 0.f), e1##S = e0##S,                     \
           e2##S = e0##S, e3##S = e0##S;                                     \
    if (odd##S) {                                                            \
        uint32_t hx1 = (uint32_t)x1c##S;                                     \
        e0##S = tbl[(hx1 ^ m00##S) & HMASK];                                 \
        e1##S = tbl[(hx1 ^ m01##S) & HMASK];                                 \
        e2##S = tbl[(hx1 ^ m10##S) & HMASK];                                 \
        e3##S = tbl[(hx1 ^ m11##S) & HMASK];                                 \
    }

#define FINISH(S, TOUT)                                                      \
    {                                                                        \
        bool b00 = (j000##S & 1), b01 = (j001##S & 1);                       \
        bool b10 = (j010##S & 1), b11 = (j011##S & 1);                       \
        float2 c000 = b00 ? make_float2(q00##S.z, q00##S.w)                  \
                          : make_float2(q00##S.x, q00##S.y);                 \
        float2 c100 = b00 ? make_float2(q00##S.x, q00##S.y)                  \
                          : make_float2(q00##S.z, q00##S.w);                 \
        float2 c001 = b01 ? make_float2(q01##S.z, q01##S.w)                  \
                          : make_float2(q01##S.x, q01##S.y);                 \
        float2 c101 = b01 ? make_float2(q01##S.x, q01##S.y)                  \
                          : make_float2(q01##S.z, q01##S.w);                 \
        float2 c010 = b10 ? make_float2(q10##S.z, q10##S.w)                  \
                          : make_float2(q10##S.x, q10##S.y);                 \
        float2 c110 = b10 ? make_float2(q10##S.x, q10##S.y)                  \
                          : make_float2(q10##S.z, q10##S.w);                 \
        float2 c011 = b11 ? make_float2(q11##S.z, q11##S.w)                  \
                          : make_float2(q11##S.x, q11##S.y);                 \
        float2 c111 = b11 ? make_float2(q11##S.x, q11##S.y)                  \
                          : make_float2(q11##S.z, q11##S.w);                 \
        if (odd##S) { c100 = e0##S; c101 = e1##S;                            \
                      c110 = e2##S; c111 = e3##S; }                          \
        float ux = 1.0f - wx##S, uy = 1.0f - wy##S, uz = 1.0f - wz##S;       \
        float w00 = ux * uy, w01 = ux * wy##S;                               \
        float w10 = wx##S * uy, w11 = wx##S * wy##S;                         \
        float f0, f1;                                                        \
        f0  = (w00 * uz)     * c000.x; f1  = (w00 * uz)     * c000.y;        \
        f0 += (w00 * wz##S)  * c001.x; f1 += (w00 * wz##S)  * c001.y;        \
        f0 += (w01 * uz)     * c010.x; f1 += (w01 * uz)     * c010.y;        \
        f0 += (w01 * wz##S)  * c011.x; f1 += (w01 * wz##S)  * c011.y;        \
        f0 += (w10 * uz)     * c100.x; f1 += (w10 * uz)     * c100.y;        \
        f0 += (w10 * wz##S)  * c101.x; f1 += (w10 * wz##S)  * c101.y;        \
        f0 += (w11 * uz)     * c110.x; f1 += (w11 * uz)     * c110.y;        \
        f0 += (w11 * wz##S)  * c111.x; f1 += (w11 * wz##S)  * c111.y;        \
        nfloat2 rr; rr.x = f0; rr.y = f1;                                    \
        __builtin_nontemporal_store(rr, (nfloat2*)&out[TOUT]);               \
    }

__global__ __launch_bounds__(256) void hash_enc_kernel(
    const float* __restrict__ pos, const float2* __restrict__ tbl,
    float2* __restrict__ out, int n)
{
    const float4* __restrict__ tbl4 = (const float4*)tbl;

    __shared__ int sres[16];
    __shared__ float spos[96];   // 32 points * 3 coords

    const int tid = threadIdx.x;
    if (tid < 16) sres[tid] = RES[tid];

    // Stage 32 positions: 24 float4 nt loads (read-once stream).
    const int p0 = blockIdx.x * 32;
    if (p0 + 32 <= n) {
        if (tid < 24) {
            nfloat4 v = __builtin_nontemporal_load(
                (const nfloat4*)(pos + (size_t)p0 * 3) + tid);
            ((nfloat4*)spos)[tid] = v;
        }
    } else {
        if (tid < 96) {
            int gi = p0 * 3 + tid;
            spos[tid] = (gi < 3 * n) ? pos[gi] : 0.0f;
        }
    }
    __syncthreads();

    const int li = tid >> 3;      // local point 0..31
    const int lA = tid & 7;       // levels 0..7
    const int lB = lA + 8;        // levels 8..15
    const int i = p0 + li;
    if (i >= n) return;

    // 8 lanes with same li broadcast from LDS.
    float x = (spos[3 * li + 0] + 1.0f) * 0.5f;
    float y = (spos[3 * li + 1] + 1.0f) * 0.5f;
    float z = (spos[3 * li + 2] + 1.0f) * 0.5f;

    // Address calc for both items, then ALL loads, then both consumes:
    // up to 16 gather requests in flight per thread.
    ADDR(A, lA)
    ADDR(B, lB)
    PAIRLOAD(A)
    PAIRLOAD(B)
    FALLBACK(A)
    FALLBACK(B)

    const int tbase = i * 16;
    FINISH(A, tbase + lA)
    FINISH(B, tbase + lB)
}

extern "C" void kernel_launch(void* const* d_in, const int* in_sizes, int n_in,
                              void* d_out, int out_size, void* d_ws, size_t ws_size,
                              hipStream_t stream) {
    const float* pos = (const float*)d_in[0];
    const float2* tbl = (const float2*)d_in[1];
    float2* out = (float2*)d_out;
    int n = in_sizes[0] / 3;
    dim3 grid((unsigned)((n + 31) / 32)), block(256);
    hash_enc_kernel<<<grid, block, 0, stream>>>(pos, tbl, out, n);
}

// Round 8
// 521.457 us; speedup vs baseline: 1.6952x; 1.0080x over previous
//
#include <hip/hip_runtime.h>
#include <cstdint>

#define P2 2654435761u
#define P3 805459861u
#define HMASK 524287u
#define NBUCK 32768   // 32^3 spatial buckets, avg 32 pts/bucket at N=1M

// nt builtins require native clang vector types.
// Round-5 lesson: nt LOADS bypass L2 (never on reused data).
// Round-6 lesson: gather working set must stay exactly the 4MB table.
// Round-7 lesson: dur is set by unique-line request count, not concurrency.
typedef float nfloat4 __attribute__((ext_vector_type(4)));
typedef float nfloat2 __attribute__((ext_vector_type(2)));

// int(16 * exp((ln2048-ln16)/15)**l), IEEE-double verified vs the numpy
// reference. All even => rm1 odd => even x0 never clamped (pair merge).
__constant__ int RES[16] = {16, 22, 30, 42, 58, 80, 111, 153,
                            212, 294, 406, 561, 776, 1072, 1482, 2048};

__device__ __forceinline__ int bucket_of(float px, float py, float pz) {
    // map [-1,1) -> [0,1) -> 32^3 cell, row-major (z fastest: z-adjacent
    // buckets share corner planes, good for the pair loads)
    int bx = min(31, max(0, (int)((px + 1.0f) * 16.0f)));
    int by = min(31, max(0, (int)((py + 1.0f) * 16.0f)));
    int bz = min(31, max(0, (int)((pz + 1.0f) * 16.0f)));
    return (bx * 32 + by) * 32 + bz;
}

__global__ __launch_bounds__(256) void zero_counts(int* c) {
    int i = blockIdx.x * 256 + threadIdx.x;
    if (i < NBUCK) c[i] = 0;
}

__global__ __launch_bounds__(256) void count_kernel(
    const float* __restrict__ pos, int* __restrict__ counts, int n) {
    int i = blockIdx.x * 256 + threadIdx.x;
    if (i >= n) return;
    atomicAdd(&counts[bucket_of(pos[3*i], pos[3*i+1], pos[3*i+2])], 1);
}

// Exclusive scan of 32768 counts in one 1024-thread block (32/thread).
__global__ __launch_bounds__(1024) void scan_kernel(int* counts) {
    __shared__ int part[1024];
    int t = threadIdx.x;
    int base = t * 32;
    int s = 0;
    #pragma unroll
    for (int j = 0; j < 32; ++j) s += counts[base + j];
    part[t] = s;
    __syncthreads();
    int orig = s;
    for (int off = 1; off < 1024; off <<= 1) {
        int v = (t >= off) ? part[t - off] : 0;
        __syncthreads();
        part[t] += v;
        __syncthreads();
    }
    int run = part[t] - orig;   // exclusive prefix of this thread's span
    for (int j = 0; j < 32; ++j) {
        int c = counts[base + j];
        counts[base + j] = run;
        run += c;
    }
}

__global__ __launch_bounds__(256) void scatter_kernel(
    const float* __restrict__ pos, int* __restrict__ counts,
    int* __restrict__ perm, int n) {
    int i = blockIdx.x * 256 + threadIdx.x;
    if (i >= n) return;
    int b = bucket_of(pos[3*i], pos[3*i+1], pos[3*i+2]);
    int slot = atomicAdd(&counts[b], 1);
    perm[slot] = i;   // perm: sorted slot -> original point index
}

// Main kernel: block = 64 spatially-bucketed points x 4 waves.
// Wave w handles levels {w, w+4, w+8, w+12} (balanced coarse/fine mix);
// within each vmem instruction all 64 lanes share ONE level and are
// spatial neighbors -> the TA merges same-line corner requests (coarse
// levels collapse toward broadcast). Fine levels stay divergent.
__global__ __launch_bounds__(256) void hash_enc_sorted(
    const float* __restrict__ pos, const float2* __restrict__ tbl,
    float2* __restrict__ out, const int* __restrict__ perm,
    int n, int usePerm)
{
    const float4* __restrict__ tbl4 = (const float4*)tbl;

    __shared__ int   sidx[64];
    __shared__ float sx[64], sy[64], sz[64];
    __shared__ float2 sout[64][17];   // +1 pad: write stride 34 banks

    const int tid = threadIdx.x;
    const int base = blockIdx.x * 64;

    if (tid < 64) {
        int gi = base + tid;
        int pi = 0;
        if (gi < n) pi = usePerm ? perm[gi] : gi;
        sidx[tid] = pi;
        float px = pos[3*pi+0], py = pos[3*pi+1], pz = pos[3*pi+2];
        sx[tid] = (px + 1.0f) * 0.5f;
        sy[tid] = (py + 1.0f) * 0.5f;
        sz[tid] = (pz + 1.0f) * 0.5f;
    }
    __syncthreads();

    const int wave = tid >> 6, lane = tid & 63;
    const float x = sx[lane], y = sy[lane], z = sz[lane];

    #pragma unroll
    for (int s = 0; s < 4; ++s) {
        const int l = wave + 4 * s;        // wave-uniform level
        const int rm1 = RES[l] - 1;        // scalar (s_load)
        const float rf = (float)rm1;

        float sxf = x * rf, syf = y * rf, szf = z * rf;
        float fx = floorf(sxf), fy = floorf(syf), fz = floorf(szf);
        float wx = sxf - fx, wy = syf - fy, wz = szf - fz;
        int x0 = (int)fx, y0 = (int)fy, z0 = (int)fz;
        int x0c = min(max(x0, 0), rm1), x1c = min(max(x0 + 1, 0), rm1);
        int y0c = min(max(y0, 0), rm1), y1c = min(max(y0 + 1, 0), rm1);
        int z0c = min(max(z0, 0), rm1), z1c = min(max(z0 + 1, 0), rm1);

        // low 19 bits of the int64 hash == low 19 bits of uint32 hash
        uint32_t hy0 = (uint32_t)y0c * P2, hy1 = (uint32_t)y1c * P2;
        uint32_t hz0 = (uint32_t)z0c * P3, hz1 = (uint32_t)z1c * P3;
        uint32_t m00 = hy0 ^ hz0, m01 = hy0 ^ hz1;
        uint32_t m10 = hy1 ^ hz0, m11 = hy1 ^ hz1;

        uint32_t hx0 = (uint32_t)x0c;
        uint32_t j000 = (hx0 ^ m00) & HMASK;
        uint32_t j001 = (hx0 ^ m01) & HMASK;
        uint32_t j010 = (hx0 ^ m10) & HMASK;
        uint32_t j011 = (hx0 ^ m11) & HMASK;

        // 4 pair loads: even x0 -> the other float4 half IS the x1 corner.
        float4 q00 = tbl4[j000 >> 1];
        float4 q01 = tbl4[j001 >> 1];
        float4 q10 = tbl4[j010 >> 1];
        float4 q11 = tbl4[j011 >> 1];

        bool b00 = (j000 & 1), b01 = (j001 & 1);
        bool b10 = (j010 & 1), b11 = (j011 & 1);
        float2 c000 = b00 ? make_float2(q00.z, q00.w) : make_float2(q00.x, q00.y);
        float2 c100 = b00 ? make_float2(q00.x, q00.y) : make_float2(q00.z, q00.w);
        float2 c001 = b01 ? make_float2(q01.z, q01.w) : make_float2(q01.x, q01.y);
        float2 c101 = b01 ? make_float2(q01.x, q01.y) : make_float2(q01.z, q01.w);
        float2 c010 = b10 ? make_float2(q10.z, q10.w) : make_float2(q10.x, q10.y);
        float2 c110 = b10 ? make_float2(q10.x, q10.y) : make_float2(q10.z, q10.w);
        float2 c011 = b11 ? make_float2(q11.z, q11.w) : make_float2(q11.x, q11.y);
        float2 c111 = b11 ? make_float2(q11.x, q11.y) : make_float2(q11.z, q11.w);

        // Odd x0: fetch the true x1 corners under exec mask.
        if (x0c & 1) {
            uint32_t hx1 = (uint32_t)x1c;
            c100 = tbl[(hx1 ^ m00) & HMASK];
            c101 = tbl[(hx1 ^ m01) & HMASK];
            c110 = tbl[(hx1 ^ m10) & HMASK];
            c111 = tbl[(hx1 ^ m11) & HMASK];
        }

        float ux = 1.0f - wx, uy = 1.0f - wy, uz = 1.0f - wz;
        float w00 = ux * uy, w01 = ux * wy, w10 = wx * uy, w11 = wx * wy;
        float f0, f1;
        f0  = (w00 * uz) * c000.x; f1  = (w00 * uz) * c000.y;
        f0 += (w00 * wz) * c001.x; f1 += (w00 * wz) * c001.y;
        f0 += (w01 * uz) * c010.x; f1 += (w01 * uz) * c010.y;
        f0 += (w01 * wz) * c011.x; f1 += (w01 * wz) * c011.y;
        f0 += (w10 * uz) * c100.x; f1 += (w10 * uz) * c100.y;
        f0 += (w10 * wz) * c101.x; f1 += (w10 * wz) * c101.y;
        f0 += (w11 * uz) * c110.x; f1 += (w11 * uz) * c110.y;
        f0 += (w11 * wz) * c111.x; f1 += (w11 * wz) * c111.y;

        sout[lane][l] = make_float2(f0, f1);
    }
    __syncthreads();

    // Coalesced output via original index: thread -> (point q, quarter).
    // Each point's 16 float2 are contiguous (128 B); 32 B per thread as
    // two 16 B nt stores (write-once output, keep L2 for the table).
    int q = tid >> 2, part = tid & 3;
    if (base + q < n) {
        int oi = sidx[q] * 16 + part * 4;   // float2 units, 32B-aligned
        float2 a = sout[q][part*4+0], b = sout[q][part*4+1];
        float2 c = sout[q][part*4+2], d = sout[q][part*4+3];
        nfloat4 v0; v0.x = a.x; v0.y = a.y; v0.z = b.x; v0.w = b.y;
        nfloat4 v1; v1.x = c.x; v1.y = c.y; v1.z = d.x; v1.w = d.y;
        __builtin_nontemporal_store(v0, (nfloat4*)&out[oi]);
        __builtin_nontemporal_store(v1, (nfloat4*)&out[oi + 2]);
    }
}

extern "C" void kernel_launch(void* const* d_in, const int* in_sizes, int n_in,
                              void* d_out, int out_size, void* d_ws, size_t ws_size,
                              hipStream_t stream) {
    const float* pos = (const float*)d_in[0];
    const float2* tbl = (const float2*)d_in[1];
    float2* out = (float2*)d_out;
    int n = in_sizes[0] / 3;

    // Workspace: counts[32768] + perm[n]  (4.3 MB at n=1M)
    size_t need = (size_t)NBUCK * 4 + (size_t)n * 4;
    int usePerm = (ws_size >= need) ? 1 : 0;
    int* counts = (int*)d_ws;
    int* perm = counts + NBUCK;

    if (usePerm) {
        zero_counts<<<dim3((NBUCK + 255) / 256), dim3(256), 0, stream>>>(counts);
        count_kernel<<<dim3((n + 255) / 256), dim3(256), 0, stream>>>(pos, counts, n);
        scan_kernel<<<dim3(1), dim3(1024), 0, stream>>>(counts);
        scatter_kernel<<<dim3((n + 255) / 256), dim3(256), 0, stream>>>(pos, counts, perm, n);
    }

    hash_enc_sorted<<<dim3((n + 63) / 64), dim3(256), 0, stream>>>(
        pos, tbl, out, perm, n, usePerm);
}